// Round 2
// baseline (139.941 us; speedup 1.0000x reference)
//
#include <hip/hip_runtime.h>
#include <hip/hip_bf16.h>

#define BATCH 16384
#define DIM   512
#define NPG   64
#define NPAIR 4096
#define NA    128   // 2*NPG rows of combined A
#define ROWS  32    // rows per block in fused kernel

typedef float f32x4 __attribute__((ext_vector_type(4)));
typedef short s16x8 __attribute__((ext_vector_type(8)));

static __device__ __forceinline__ unsigned short f2bf(float f) {
    union { float f; unsigned u; } v; v.f = f;
    unsigned r = (v.u + 0x7FFFu + ((v.u >> 16) & 1u)) >> 16;
    return (unsigned short)r;
}

// K1: A[j][d] = sum_k proto[j][k] * W[d][koff+k],  j in [0,128), d in [0,512)
__global__ void k1_mixA(const float* __restrict__ proto, const float* __restrict__ W,
                        float* __restrict__ Af, unsigned short* __restrict__ Ab) {
    int gid = blockIdx.x * blockDim.x + threadIdx.x;   // 65536 threads
    int j = gid & (NA - 1);
    int d = gid >> 7;
    int koff = (j < NPG) ? 0 : DIM;
    const float4* pr = (const float4*)(proto + j * DIM);
    const float4* wr = (const float4*)(W + d * (2 * DIM) + koff);
    float a0 = 0.f, a1 = 0.f, a2 = 0.f, a3 = 0.f;
#pragma unroll 4
    for (int k4 = 0; k4 < DIM / 4; ++k4) {
        float4 p = pr[k4], w = wr[k4];
        a0 += p.x * w.x; a1 += p.y * w.y; a2 += p.z * w.z; a3 += p.w * w.w;
    }
    float a = (a0 + a1) + (a2 + a3);
    Af[j * DIM + d] = a;
    Ab[j * DIM + d] = f2bf(a);
}

// K2: pp[j*64+l] = || A[j] + A[64+l] + b ||^2   (one wave per pair)
__global__ void k2_pp(const float* __restrict__ Af, const float* __restrict__ bm,
                      float* __restrict__ pp) {
    int wave = (blockIdx.x * blockDim.x + threadIdx.x) >> 6;  // 4096 waves
    int lane = threadIdx.x & 63;
    int j = wave >> 6, l = wave & 63;
    const float4* r0 = (const float4*)(Af + j * DIM);
    const float4* r1 = (const float4*)(Af + (NPG + l) * DIM);
    const float4* bb = (const float4*)bm;
    float acc = 0.f;
#pragma unroll
    for (int i = 0; i < 2; ++i) {
        int idx = lane * 2 + i;
        float4 v0 = r0[idx], v1 = r1[idx], vb = bb[idx];
        float s;
        s = v0.x + v1.x + vb.x; acc += s * s;
        s = v0.y + v1.y + vb.y; acc += s * s;
        s = v0.z + v1.z + vb.z; acc += s * s;
        s = v0.w + v1.w + vb.w; acc += s * s;
    }
#pragma unroll
    for (int off = 32; off > 0; off >>= 1) acc += __shfl_xor(acc, off);
    if (lane == 0) pp[wave] = acc;
}

// KC: fused  U = X@A^T (MFMA)  +  xx/w  +  epilogue writes out directly.
// 512 blocks x 256 threads. Block owns rows m0..m0+31.
// Wave wv: rpair = wv>>1 picks 16-row half, chalf = wv&1 picks 64-col half.
__global__ void kc_fused(const float* __restrict__ x, const unsigned short* __restrict__ Ab,
                         const float* __restrict__ bm, const float* __restrict__ pp,
                         float* __restrict__ out) {
    __shared__ float Ut[ROWS][NA];     // 16 KB
    __shared__ float pps[NPAIR];       // 16 KB
    __shared__ float xs[ROWS], wsum[ROWS];

    int t = threadIdx.x;
    int lane = t & 63;
    int wv = t >> 6;
    int r = lane & 15, g = lane >> 4;
    int m0 = blockIdx.x * ROWS;
    int rpair = wv >> 1;               // 0 or 1
    int chalf = wv & 1;                // 0 or 1
    int cbase = chalf * 64;

    // stage pp into LDS (overlaps with GEMM issue)
#pragma unroll
    for (int i = 0; i < 4; ++i)
        ((float4*)pps)[i * 256 + t] = ((const float4*)pp)[i * 256 + t];

    f32x4 acc[4];
#pragma unroll
    for (int ct = 0; ct < 4; ++ct) acc[ct] = (f32x4){0.f, 0.f, 0.f, 0.f};

    const float* xrow = x + (size_t)(m0 + rpair * 16 + r) * DIM;
    float axx = 0.f, aw = 0.f;

    for (int k0 = 0; k0 < DIM; k0 += 32) {
        int kb = k0 + g * 8;
        float4 xa = *(const float4*)(xrow + kb);
        float4 xb = *(const float4*)(xrow + kb + 4);
        if (chalf == 0) {  // xx / w partials (one col-half only, avoids dup)
            float4 b0 = *(const float4*)(bm + kb);
            float4 b1 = *(const float4*)(bm + kb + 4);
            axx += xa.x * xa.x + xa.y * xa.y + xa.z * xa.z + xa.w * xa.w
                 + xb.x * xb.x + xb.y * xb.y + xb.z * xb.z + xb.w * xb.w;
            aw  += xa.x * b0.x + xa.y * b0.y + xa.z * b0.z + xa.w * b0.w
                 + xb.x * b1.x + xb.y * b1.y + xb.z * b1.z + xb.w * b1.w;
        }
        s16x8 xf;
        xf[0] = (short)f2bf(xa.x); xf[1] = (short)f2bf(xa.y);
        xf[2] = (short)f2bf(xa.z); xf[3] = (short)f2bf(xa.w);
        xf[4] = (short)f2bf(xb.x); xf[5] = (short)f2bf(xb.y);
        xf[6] = (short)f2bf(xb.z); xf[7] = (short)f2bf(xb.w);
#pragma unroll
        for (int ct = 0; ct < 4; ++ct) {
            s16x8 bf = *(const s16x8*)(Ab + (size_t)(cbase + ct * 16 + r) * DIM + kb);
            acc[ct] = __builtin_amdgcn_mfma_f32_16x16x32_bf16(xf, bf, acc[ct], 0, 0, 0);
        }
    }

    // U tile -> LDS.  C/D layout: col = lane&15, row = (lane>>4)*4 + reg
#pragma unroll
    for (int ct = 0; ct < 4; ++ct)
#pragma unroll
        for (int rr = 0; rr < 4; ++rr)
            Ut[rpair * 16 + g * 4 + rr][cbase + ct * 16 + r] = acc[ct][rr];

    if (chalf == 0) {
        axx += __shfl_xor(axx, 16); axx += __shfl_xor(axx, 32);
        aw  += __shfl_xor(aw, 16);  aw  += __shfl_xor(aw, 32);
        if (g == 0) { xs[rpair * 16 + r] = axx; wsum[rpair * 16 + r] = aw; }
    }
    __syncthreads();

    // epilogue: out[b][j*64+l] = xx[b] + pp - 2*(U[b][j] + U[b][64+l] + w[b])
    for (int rr = 0; rr < ROWS; ++rr) {
        float base0 = xs[rr] - 2.0f * wsum[rr];
        const float* Ur = Ut[rr];
        float* orow = out + (size_t)(m0 + rr) * NPAIR;
#pragma unroll
        for (int i = 0; i < 4; ++i) {
            int idx = (i * 256 + t) * 4;
            int j = idx >> 6, l = idx & 63;
            float uj = Ur[j];
            float4 v4 = *(const float4*)(Ur + NPG + l);
            float4 p4 = *(const float4*)(pps + idx);
            float base = base0 - 2.0f * uj;
            float4 o;
            o.x = base + p4.x - 2.0f * v4.x;
            o.y = base + p4.y - 2.0f * v4.y;
            o.z = base + p4.z - 2.0f * v4.z;
            o.w = base + p4.w - 2.0f * v4.w;
            *(float4*)(orow + idx) = o;
        }
    }
}

extern "C" void kernel_launch(void* const* d_in, const int* in_sizes, int n_in,
                              void* d_out, int out_size, void* d_ws, size_t ws_size,
                              hipStream_t stream) {
    const float* x     = (const float*)d_in[0];   // [16384, 512]
    const float* proto = (const float*)d_in[1];   // [2, 64, 512] -> flat [128, 512]
    const float* Wmix  = (const float*)d_in[2];   // [512, 1024]
    const float* bmix  = (const float*)d_in[3];   // [512]
    float* out = (float*)d_out;

    float* ws = (float*)d_ws;
    float*          Af = ws;                                   // 65536 f32
    unsigned short* Ab = (unsigned short*)(ws + 65536);        // 65536 bf16
    float*          pp = ws + 65536 + 32768;                   // 4096 f32

    k1_mixA <<<256, 256, 0, stream>>>(proto, Wmix, Af, Ab);
    k2_pp   <<<1024, 256, 0, stream>>>(Af, bmix, pp);
    kc_fused<<<512, 256, 0, stream>>>(x, Ab, bmix, pp, out);
}

// Round 3
// 117.226 us; speedup vs baseline: 1.1938x; 1.1938x over previous
//
#include <hip/hip_runtime.h>
#include <hip/hip_bf16.h>

#define BATCH 16384
#define DIM   512
#define NPG   64
#define NPAIR 4096
#define NA    128

typedef float f32x4 __attribute__((ext_vector_type(4)));
typedef short s16x8 __attribute__((ext_vector_type(8)));

static __device__ __forceinline__ unsigned short f2bf(float f) {
    union { float f; unsigned u; } v; v.f = f;
    unsigned r = (v.u + 0x7FFFu + ((v.u >> 16) & 1u)) >> 16;
    return (unsigned short)r;
}

// K1: A[j][d] = sum_k proto[j][k] * W[d][koff+k],  j in [0,128), d in [0,512)
__global__ void k1_mixA(const float* __restrict__ proto, const float* __restrict__ W,
                        float* __restrict__ Af, unsigned short* __restrict__ Ab) {
    int gid = blockIdx.x * blockDim.x + threadIdx.x;   // 65536 threads
    int j = gid & (NA - 1);
    int d = gid >> 7;
    int koff = (j < NPG) ? 0 : DIM;
    const float4* pr = (const float4*)(proto + j * DIM);
    const float4* wr = (const float4*)(W + d * (2 * DIM) + koff);
    float a0 = 0.f, a1 = 0.f, a2 = 0.f, a3 = 0.f;
#pragma unroll 4
    for (int k4 = 0; k4 < DIM / 4; ++k4) {
        float4 p = pr[k4], w = wr[k4];
        a0 += p.x * w.x; a1 += p.y * w.y; a2 += p.z * w.z; a3 += p.w * w.w;
    }
    float a = (a0 + a1) + (a2 + a3);
    Af[j * DIM + d] = a;
    Ab[j * DIM + d] = f2bf(a);
}

// K2: pp[j*64+l] = || A[j] + A[64+l] + b ||^2   (one wave per pair)
__global__ void k2_pp(const float* __restrict__ Af, const float* __restrict__ bm,
                      float* __restrict__ pp) {
    int wave = (blockIdx.x * blockDim.x + threadIdx.x) >> 6;  // 4096 waves
    int lane = threadIdx.x & 63;
    int j = wave >> 6, l = wave & 63;
    const float4* r0 = (const float4*)(Af + j * DIM);
    const float4* r1 = (const float4*)(Af + (NPG + l) * DIM);
    const float4* bb = (const float4*)bm;
    float acc = 0.f;
#pragma unroll
    for (int i = 0; i < 2; ++i) {
        int idx = lane * 2 + i;
        float4 v0 = r0[idx], v1 = r1[idx], vb = bb[idx];
        float s;
        s = v0.x + v1.x + vb.x; acc += s * s;
        s = v0.y + v1.y + vb.y; acc += s * s;
        s = v0.z + v1.z + vb.z; acc += s * s;
        s = v0.w + v1.w + vb.w; acc += s * s;
    }
#pragma unroll
    for (int off = 32; off > 0; off >>= 1) acc += __shfl_xor(acc, off);
    if (lane == 0) pp[wave] = acc;
}

// K3: rb[b] = ||x_b||^2 - 2 * (x_b . b_mix)   (one wave per row)
__global__ void k3_rb(const float* __restrict__ x, const float* __restrict__ bm,
                      float* __restrict__ rb) {
    int wave = (blockIdx.x * blockDim.x + threadIdx.x) >> 6;  // 16384 waves
    int lane = threadIdx.x & 63;
    const float4* xr = (const float4*)(x + (size_t)wave * DIM);
    const float4* bb = (const float4*)bm;
    float axx = 0.f, aw = 0.f;
#pragma unroll
    for (int i = 0; i < 2; ++i) {
        int idx = lane * 2 + i;
        float4 v = xr[idx], vb = bb[idx];
        axx += v.x * v.x + v.y * v.y + v.z * v.z + v.w * v.w;
        aw  += v.x * vb.x + v.y * vb.y + v.z * vb.z + v.w * vb.w;
    }
#pragma unroll
    for (int off = 32; off > 0; off >>= 1) {
        axx += __shfl_xor(axx, off);
        aw  += __shfl_xor(aw, off);
    }
    if (lane == 0) rb[wave] = axx - 2.0f * aw;
}

// K4: [U|V] = X @ A^T via bf16 MFMA. U (cols 0..63) -> f32, V (cols 64..127) -> bf16.
__global__ void k4_gemm(const float* __restrict__ x, const unsigned short* __restrict__ Ab,
                        float* __restrict__ Uf, unsigned short* __restrict__ Vb) {
    int lane = threadIdx.x & 63;
    int wv = threadIdx.x >> 6;
    int m0 = blockIdx.x * 64 + wv * 16;
    int r = lane & 15, g = lane >> 4;
    f32x4 acc[8];
#pragma unroll
    for (int ct = 0; ct < 8; ++ct) acc[ct] = (f32x4){0.f, 0.f, 0.f, 0.f};
    const float* xrow = x + (size_t)(m0 + r) * DIM;
    for (int k0 = 0; k0 < DIM; k0 += 32) {
        int kb = k0 + g * 8;
        float4 xa = *(const float4*)(xrow + kb);
        float4 xb = *(const float4*)(xrow + kb + 4);
        s16x8 xf;
        xf[0] = (short)f2bf(xa.x); xf[1] = (short)f2bf(xa.y);
        xf[2] = (short)f2bf(xa.z); xf[3] = (short)f2bf(xa.w);
        xf[4] = (short)f2bf(xb.x); xf[5] = (short)f2bf(xb.y);
        xf[6] = (short)f2bf(xb.z); xf[7] = (short)f2bf(xb.w);
#pragma unroll
        for (int ct = 0; ct < 8; ++ct) {
            s16x8 bf = *(const s16x8*)(Ab + (size_t)(ct * 16 + r) * DIM + kb);
            acc[ct] = __builtin_amdgcn_mfma_f32_16x16x32_bf16(xf, bf, acc[ct], 0, 0, 0);
        }
    }
    // C/D layout: col = lane&15 (A-row n), row = (lane>>4)*4 + reg (x-row m)
#pragma unroll
    for (int ct = 0; ct < 4; ++ct)
#pragma unroll
        for (int rr = 0; rr < 4; ++rr)
            Uf[(size_t)(m0 + g * 4 + rr) * 64 + ct * 16 + r] = acc[ct][rr];
#pragma unroll
    for (int ct = 4; ct < 8; ++ct)
#pragma unroll
        for (int rr = 0; rr < 4; ++rr)
            Vb[(size_t)(m0 + g * 4 + rr) * 64 + (ct - 4) * 16 + r] = f2bf(acc[ct][rr]);
}

// KO: out[b][p] = pp[p] + rb[b] - 2U[b][p>>6] - 2V[b][p&63]
// Transposed MFMA tiles: m-side = p (16), n-side = batch (16).
// A-operand = one-hot selector (-2 at k = l(p)), B-operand = Vb row.
// acc init = pp[p] + (rb[b] - 2U[b][j]).
__global__ void kO_epilogue(const float* __restrict__ Uf, const unsigned short* __restrict__ Vb,
                            const float* __restrict__ rb, const float* __restrict__ pp,
                            float* __restrict__ out) {
    __shared__ float rbU[4][256];
    int t = threadIdx.x;
    int lane = t & 63;
    int w = t >> 6;
    int r = lane & 15, g = lane >> 4;
    int col_blk = blockIdx.x & 15;
    int row_blk = blockIdx.x >> 4;
    int p0 = col_blk * 256;
    int m0 = row_blk * 256;
    int jbase = p0 >> 6;   // = col_blk * 4

    // phase 0: rbU[jj][row] = rb[m0+row] - 2*U[m0+row][jbase+jj]
    {
        float rbv = rb[m0 + t];
        const float* urow = Uf + (size_t)(m0 + t) * 64 + jbase;
#pragma unroll
        for (int jj = 0; jj < 4; ++jj)
            rbU[jj][t] = rbv - 2.0f * urow[jj];
    }

    // selector A-frags: variant v (l0 = v*16): nonzero elem where g*8+e == (v&1)*16 + r
    s16x8 sf[4];
#pragma unroll
    for (int v = 0; v < 4; ++v) {
        int pos = ((v & 1) << 4) + r;   // in [0,32) within kk-slice v>>1
        int hit_g = pos >> 3;
        int hit_e = pos & 7;
#pragma unroll
        for (int e = 0; e < 8; ++e)
            sf[v][e] = (g == hit_g && e == hit_e) ? (short)0xC000 : (short)0;  // -2.0 bf16
    }

    // preload pp4 for 16 p-tiles: lane's 4 p-values = p0 + mt*16 + g*4 + (0..3)
    f32x4 pp4[16];
#pragma unroll
    for (int mt = 0; mt < 16; ++mt)
        pp4[mt] = *(const f32x4*)(pp + p0 + mt * 16 + g * 4);

    __syncthreads();

    // wave w handles b-tiles bt = w*4 .. w*4+3
#pragma unroll
    for (int bti = 0; bti < 4; ++bti) {
        int bt = w * 4 + bti;
        int brow = m0 + bt * 16 + r;     // this lane's batch row
        const unsigned short* vrow = Vb + (size_t)brow * 64;
        s16x8 vb0 = *(const s16x8*)(vrow + g * 8);
        s16x8 vb1 = *(const s16x8*)(vrow + 32 + g * 8);
        float rbu0 = rbU[0][bt * 16 + r];
        float rbu1 = rbU[1][bt * 16 + r];
        float rbu2 = rbU[2][bt * 16 + r];
        float rbu3 = rbU[3][bt * 16 + r];
        float* obase = out + (size_t)brow * NPAIR + p0 + g * 4;
#pragma unroll
        for (int mt = 0; mt < 16; ++mt) {
            int v = mt & 3;
            float ru = (mt >> 2) == 0 ? rbu0 : (mt >> 2) == 1 ? rbu1 : (mt >> 2) == 2 ? rbu2 : rbu3;
            f32x4 c;
            c[0] = pp4[mt][0] + ru;
            c[1] = pp4[mt][1] + ru;
            c[2] = pp4[mt][2] + ru;
            c[3] = pp4[mt][3] + ru;
            c = __builtin_amdgcn_mfma_f32_16x16x32_bf16(sf[v], (v >> 1) ? vb1 : vb0, c, 0, 0, 0);
            *(f32x4*)(obase + mt * 16) = c;
        }
    }
}

extern "C" void kernel_launch(void* const* d_in, const int* in_sizes, int n_in,
                              void* d_out, int out_size, void* d_ws, size_t ws_size,
                              hipStream_t stream) {
    const float* x     = (const float*)d_in[0];   // [16384, 512]
    const float* proto = (const float*)d_in[1];   // [2, 64, 512] -> flat [128, 512]
    const float* Wmix  = (const float*)d_in[2];   // [512, 1024]
    const float* bmix  = (const float*)d_in[3];   // [512]
    float* out = (float*)d_out;

    float* ws = (float*)d_ws;
    float*          Af = ws;                          // 65536 f32
    float*          pp = ws + 65536;                  // 4096 f32
    float*          rbv= ws + 69632;                  // 16384 f32
    float*          Uf = ws + 86016;                  // 16384*64 f32
    unsigned short* Ab = (unsigned short*)(ws + 86016 + 1048576);  // 65536 bf16
    unsigned short* Vb = Ab + 65536;                  // 16384*64 bf16

    k1_mixA    <<<256, 256, 0, stream>>>(proto, Wmix, Af, Ab);
    k2_pp      <<<1024, 256, 0, stream>>>(Af, bmix, pp);
    k3_rb      <<<4096, 256, 0, stream>>>(x, bmix, rbv);
    k4_gemm    <<<256, 256, 0, stream>>>(x, Ab, Uf, Vb);
    kO_epilogue<<<1024, 256, 0, stream>>>(Uf, Vb, rbv, pp, out);
}

// Round 4
// 100.496 us; speedup vs baseline: 1.3925x; 1.1665x over previous
//
#include <hip/hip_runtime.h>
#include <hip/hip_bf16.h>

#define BATCH 16384
#define DIM   512
#define NPG   64
#define NPAIR 4096
#define NA    128
#define GEMM_BLOCKS 1024

typedef float f32x4 __attribute__((ext_vector_type(4)));
typedef short s16x8 __attribute__((ext_vector_type(8)));
typedef unsigned short u16;

static __device__ __forceinline__ u16 f2bf(float f) {
    union { float f; unsigned u; } v; v.f = f;
    unsigned r = (v.u + 0x7FFFu + ((v.u >> 16) & 1u)) >> 16;
    return (u16)r;
}

// kA: A[j][d] = proto[j] . W[d][koff:koff+512], K-split x2 across lane pairs.
// 512 blocks x 256 threads. gid: h=bit0 (K half), j=(gid>>1)&127, d=gid>>8.
__global__ __launch_bounds__(256) void kA_mixA(const float* __restrict__ proto,
                                               const float* __restrict__ W,
                                               float* __restrict__ Af,
                                               u16* __restrict__ Ab) {
    int gid = blockIdx.x * 256 + threadIdx.x;
    int h = gid & 1;
    int j = (gid >> 1) & 127;
    int d = gid >> 8;
    int koff = (j < NPG ? 0 : DIM) + h * (DIM / 2);
    const float4* pr = (const float4*)(proto + j * DIM + h * (DIM / 2));
    const float4* wr = (const float4*)(W + d * (2 * DIM) + koff);
    float a0 = 0.f, a1 = 0.f, a2 = 0.f, a3 = 0.f;
#pragma unroll 4
    for (int k4 = 0; k4 < DIM / 8; ++k4) {   // 64 float4 iters (256 elems)
        float4 p = pr[k4], w = wr[k4];
        a0 += p.x * w.x; a1 += p.y * w.y; a2 += p.z * w.z; a3 += p.w * w.w;
    }
    float a = (a0 + a1) + (a2 + a3);
    a += __shfl_xor(a, 1);                   // combine K halves
    if (h == 0) {
        Af[j * DIM + d] = a;
        Ab[j * DIM + d] = f2bf(a);
    }
}

// kB: blocks < GEMM_BLOCKS: 16-row slab of U = X@A^T via MFMA, x staged once
// as bf16 in XOR-swizzled LDS; rb fused from the same loads.
// blocks >= GEMM_BLOCKS: pp pairs (8 per block).
__global__ __launch_bounds__(512, 4) void kB_main(const float* __restrict__ x,
                                                  const u16* __restrict__ Ab,
                                                  const float* __restrict__ Af,
                                                  const float* __restrict__ bm,
                                                  float* __restrict__ U,
                                                  float* __restrict__ rb,
                                                  float* __restrict__ pp) {
    __shared__ u16   xsb[16 * 512];          // 16 KB, XOR-swizzled bf16 slab
    __shared__ float xxs[16], ws2[16];
    int bid = blockIdx.x;
    int t = threadIdx.x;
    int lane = t & 63;
    int w = t >> 6;

    if (bid < GEMM_BLOCKS) {
        int m0 = bid * 16;
        // ---- stage x slab + rb partials. thread t: row=t>>5, cols (t&31)*4 + i*128
        int row = t >> 5;
        int c0 = (t & 31) * 4;
        const float* xrow = x + (size_t)(m0 + row) * DIM;
        float xx = 0.f, wdot = 0.f;
#pragma unroll
        for (int i = 0; i < 4; ++i) {
            int col = c0 + i * 128;
            float4 v = *(const float4*)(xrow + col);
            float4 b = *(const float4*)(bm + col);
            xx   += v.x * v.x + v.y * v.y + v.z * v.z + v.w * v.w;
            wdot += v.x * b.x + v.y * b.y + v.z * b.z + v.w * b.w;
            ushort4 hv;
            hv.x = f2bf(v.x); hv.y = f2bf(v.y); hv.z = f2bf(v.z); hv.w = f2bf(v.w);
            int byte = (row * 1024 + col * 2) ^ ((row & 7) << 4);
            *(ushort4*)((char*)xsb + byte) = hv;
        }
        // reduce within the 32-thread group that owns this row
#pragma unroll
        for (int off = 16; off > 0; off >>= 1) {
            xx   += __shfl_xor(xx, off);
            wdot += __shfl_xor(wdot, off);
        }
        if ((t & 31) == 0) { xxs[row] = xx; ws2[row] = wdot; }
        __syncthreads();
        if (t < 16) rb[m0 + t] = xxs[t] - 2.0f * ws2[t];

        // ---- MFMA: wave w owns col-tile ct=w (A rows ct*16..+15), K=512
        int r = lane & 15, g = lane >> 4;
        int ct = w;
        f32x4 acc = (f32x4){0.f, 0.f, 0.f, 0.f};
        const u16* brow = Ab + (size_t)(ct * 16 + r) * DIM;
#pragma unroll
        for (int k0 = 0; k0 < 16; ++k0) {
            int byte = (r * 1024 + k0 * 64 + g * 16) ^ ((r & 7) << 4);
            s16x8 af = *(const s16x8*)((const char*)xsb + byte);
            s16x8 bf = *(const s16x8*)(brow + k0 * 32 + g * 8);
            acc = __builtin_amdgcn_mfma_f32_16x16x32_bf16(af, bf, acc, 0, 0, 0);
        }
        // C/D: col = lane&15 -> A-row (ct*16+r), row = g*4+reg -> x-row
#pragma unroll
        for (int rr = 0; rr < 4; ++rr)
            U[(size_t)(m0 + g * 4 + rr) * NA + ct * 16 + r] = acc[rr];
    } else {
        // ---- pp: wave computes one pair
        int pidx = (bid - GEMM_BLOCKS) * 8 + w;    // [0, 4096)
        int j = pidx >> 6, l = pidx & 63;
        const float4* r0 = (const float4*)(Af + j * DIM);
        const float4* r1 = (const float4*)(Af + (NPG + l) * DIM);
        const float4* bb = (const float4*)bm;
        float acc = 0.f;
#pragma unroll
        for (int i = 0; i < 2; ++i) {
            int idx = lane * 2 + i;
            float4 v0 = r0[idx], v1 = r1[idx], vb = bb[idx];
            float s;
            s = v0.x + v1.x + vb.x; acc += s * s;
            s = v0.y + v1.y + vb.y; acc += s * s;
            s = v0.z + v1.z + vb.z; acc += s * s;
            s = v0.w + v1.w + vb.w; acc += s * s;
        }
#pragma unroll
        for (int off = 32; off > 0; off >>= 1) acc += __shfl_xor(acc, off);
        if (lane == 0) pp[pidx] = acc;
    }
}

// kC: out[b][j*64+l] = pp[p] + rb[b] - 2*(U[b][j] + U[b][64+l])
// 4096 blocks x 256 threads, 4 rows per block. Stores: 1KB/wave contiguous.
__global__ __launch_bounds__(256) void kC_out(const float* __restrict__ U,
                                              const float* __restrict__ rb,
                                              const float* __restrict__ pp,
                                              float* __restrict__ out) {
    int t = threadIdx.x;
    int m0 = blockIdx.x * 4;
#pragma unroll
    for (int rr = 0; rr < 4; ++rr) {
        int brow = m0 + rr;
        float base0 = rb[brow];
        const float* Ur = U + (size_t)brow * NA;
        float* orow = out + (size_t)brow * NPAIR;
#pragma unroll
        for (int i = 0; i < 4; ++i) {
            int idx = (i * 256 + t) * 4;
            int j = idx >> 6, l = idx & 63;
            float uj = Ur[j];
            float4 v4 = *(const float4*)(Ur + NPG + l);
            float4 p4 = *(const float4*)(pp + idx);
            float s = base0 - 2.0f * uj;
            float4 o;
            o.x = s + p4.x - 2.0f * v4.x;
            o.y = s + p4.y - 2.0f * v4.y;
            o.z = s + p4.z - 2.0f * v4.z;
            o.w = s + p4.w - 2.0f * v4.w;
            *(float4*)(orow + idx) = o;
        }
    }
}

extern "C" void kernel_launch(void* const* d_in, const int* in_sizes, int n_in,
                              void* d_out, int out_size, void* d_ws, size_t ws_size,
                              hipStream_t stream) {
    const float* x     = (const float*)d_in[0];   // [16384, 512]
    const float* proto = (const float*)d_in[1];   // [2, 64, 512] -> flat [128, 512]
    const float* Wmix  = (const float*)d_in[2];   // [512, 1024]
    const float* bmix  = (const float*)d_in[3];   // [512]
    float* out = (float*)d_out;

    float* ws = (float*)d_ws;
    float* Af = ws;                         // 65536 f32
    float* pp = ws + 65536;                 // 4096 f32
    float* rb = ws + 69632;                 // 16384 f32
    float* U  = ws + 86016;                 // 16384*128 f32 (8 MB)
    u16*   Ab = (u16*)(ws + 86016 + 16384 * 128);   // 65536 bf16

    kA_mixA<<<512, 256, 0, stream>>>(proto, Wmix, Af, Ab);
    kB_main<<<GEMM_BLOCKS + 512, 512, 0, stream>>>(x, Ab, Af, bmix, U, rb, pp);
    kC_out <<<4096, 256, 0, stream>>>(U, rb, pp, out);
}